// Round 1
// baseline (208.556 us; speedup 1.0000x reference)
//
#include <hip/hip_runtime.h>
#include <hip/hip_bf16.h>
#include <cstddef>

// Problem constants (fixed by init_kwargs)
#define DIMC   128
#define NHEADS 8
#define HDIM   16
#define DD     5
#define HH     24
#define WW_    48
#define NPOS   (DD * HH * WW_)     // 5760
#define NNB    245                 // 5*7*7
#define SCALE  0.25f               // hd^-0.5 = 1/4

// ---------------------------------------------------------------------------
// Tiled fp32 GEMM: C[M][N] = A[M][K] @ B[N][K]^T + bias[N]
// A row-major lda, B row-major ldb (K contiguous), C row-major ldc.
// BM=BN=64, BK=64, 256 threads, 4x4 micro-tile with strided (x16) mapping
// (keeps LDS reads at <=2-way bank aliasing, which is free on CDNA4).
// ---------------------------------------------------------------------------
template <int BM, int BN, int BK>
__global__ __launch_bounds__(256) void gemm_bias_kernel(
    const float* __restrict__ A, int lda,
    const float* __restrict__ B, int ldb,
    const float* __restrict__ bias,
    float* __restrict__ C, int ldc,
    int M, int N, int K)
{
    __shared__ __align__(16) float As[BM][BK + 4];
    __shared__ __align__(16) float Bs[BN][BK + 4];

    const int tid = threadIdx.x;
    const int bm = blockIdx.y * BM;
    const int bn = blockIdx.x * BN;
    const int tx = tid & 15;   // 0..15
    const int ty = tid >> 4;   // 0..15

    float acc[4][4] = {};

    for (int k0 = 0; k0 < K; k0 += BK) {
        // stage A and B tiles: BM*BK/4 float4 loads spread over 256 threads
        #pragma unroll
        for (int i = tid; i < BM * BK / 4; i += 256) {
            const int r = i / (BK / 4);
            const int c = (i % (BK / 4)) * 4;
            const float4 va = *(const float4*)(A + (size_t)(bm + r) * lda + k0 + c);
            As[r][c + 0] = va.x; As[r][c + 1] = va.y;
            As[r][c + 2] = va.z; As[r][c + 3] = va.w;
            const float4 vb = *(const float4*)(B + (size_t)(bn + r) * ldb + k0 + c);
            Bs[r][c + 0] = vb.x; Bs[r][c + 1] = vb.y;
            Bs[r][c + 2] = vb.z; Bs[r][c + 3] = vb.w;
        }
        __syncthreads();

        #pragma unroll 8
        for (int k = 0; k < BK; ++k) {
            float a[4], b[4];
            #pragma unroll
            for (int i = 0; i < 4; ++i) a[i] = As[ty + i * 16][k];
            #pragma unroll
            for (int j = 0; j < 4; ++j) b[j] = Bs[tx + j * 16][k];
            #pragma unroll
            for (int i = 0; i < 4; ++i)
                #pragma unroll
                for (int j = 0; j < 4; ++j)
                    acc[i][j] += a[i] * b[j];
        }
        __syncthreads();
    }

    #pragma unroll
    for (int i = 0; i < 4; ++i) {
        const int row = bm + ty + i * 16;
        float* crow = C + (size_t)row * ldc + bn;
        #pragma unroll
        for (int j = 0; j < 4; ++j) {
            const int col = tx + j * 16;
            crow[col] = acc[i][j] + bias[bn + col];
        }
    }
}

// ---------------------------------------------------------------------------
// Fused neighborhood attention: one block per position p.
// qkv layout: [P][384] = [q(128) | k(128) | v(128)]
// Writes attn_out[P][128] (pre-projection).
// ---------------------------------------------------------------------------
__global__ __launch_bounds__(256) void attn_kernel(
    const float* __restrict__ qkv,
    float* __restrict__ attn_out)
{
    __shared__ __align__(16) float q_s[DIMC];
    __shared__ int nidx_s[256];
    __shared__ float sc_s[NHEADS * 248];   // scores, padded stride
    __shared__ float red_s[2][DIMC];

    const int p   = blockIdx.x;
    const int tid = threadIdx.x;

    // decompose position
    const int d   = p / (HH * WW_);
    const int rem = p % (HH * WW_);
    const int hy  = rem / WW_;
    const int wx  = rem % WW_;

    if (tid < DIMC) q_s[tid] = qkv[(size_t)p * 384 + tid];
    if (tid < NNB) {
        const int od = tid / 49;
        const int r2 = tid % 49;
        const int oh = r2 / 7;
        const int ow = r2 % 7;
        int dn = d + od - 2;  dn += (dn < 0) ? DD  : 0;  dn -= (dn >= DD)  ? DD  : 0;
        int hn = hy + oh - 3; hn += (hn < 0) ? HH  : 0;  hn -= (hn >= HH)  ? HH  : 0;
        int wn = wx + ow - 3; wn += (wn < 0) ? WW_ : 0;  wn -= (wn >= WW_) ? WW_ : 0;
        nidx_s[tid] = (dn * HH + hn) * WW_ + wn;
    }
    __syncthreads();

    // ---- Phase 1: scores[h][j] = scale * dot(q[h], k[nidx[j]][h]) ----
    {
        const int h  = tid & 7;    // head
        const int jb = tid >> 3;   // 32 neighbors per pass
        const float4* qp = (const float4*)(q_s + h * HDIM);
        const float4 q0 = qp[0], q1 = qp[1], q2 = qp[2], q3 = qp[3];
        for (int j = jb; j < NNB; j += 32) {
            const int row = nidx_s[j];
            const float4* kp = (const float4*)(qkv + (size_t)row * 384 + 128 + h * HDIM);
            const float4 k0 = kp[0], k1 = kp[1], k2 = kp[2], k3 = kp[3];
            float dot = q0.x * k0.x + q0.y * k0.y + q0.z * k0.z + q0.w * k0.w
                      + q1.x * k1.x + q1.y * k1.y + q1.z * k1.z + q1.w * k1.w
                      + q2.x * k2.x + q2.y * k2.y + q2.z * k2.z + q2.w * k2.w
                      + q3.x * k3.x + q3.y * k3.y + q3.z * k3.z + q3.w * k3.w;
            sc_s[h * 248 + j] = dot * SCALE;
        }
    }
    __syncthreads();

    // ---- Phase 2: softmax over 245 neighbors, 32 threads per head ----
    {
        const int h = tid >> 5;
        const int t = tid & 31;
        float* s = sc_s + h * 248;
        float m = -1e30f;
        for (int j = t; j < NNB; j += 32) m = fmaxf(m, s[j]);
        #pragma unroll
        for (int o = 16; o > 0; o >>= 1) m = fmaxf(m, __shfl_xor(m, o, 32));
        float sum = 0.f;
        for (int j = t; j < NNB; j += 32) {
            const float e = __expf(s[j] - m);
            s[j] = e;
            sum += e;
        }
        #pragma unroll
        for (int o = 16; o > 0; o >>= 1) sum += __shfl_xor(sum, o, 32);
        const float inv = 1.0f / sum;
        for (int j = t; j < NNB; j += 32) s[j] *= inv;
    }
    __syncthreads();

    // ---- Phase 3: out[c] = sum_j attn[h(c)][j] * v[nidx[j]][c] ----
    {
        const int c    = tid & 127;
        const int half = tid >> 7;
        const int h    = c >> 4;
        float acc = 0.f;
        for (int j = half; j < NNB; j += 2) {
            const int row = nidx_s[j];
            acc += sc_s[h * 248 + j] * qkv[(size_t)row * 384 + 256 + c];
        }
        red_s[half][c] = acc;
    }
    __syncthreads();

    if (tid < DIMC) {
        attn_out[(size_t)p * DIMC + tid] = red_s[0][tid] + red_s[1][tid];
    }
}

// ---------------------------------------------------------------------------
extern "C" void kernel_launch(void* const* d_in, const int* in_sizes, int n_in,
                              void* d_out, int out_size, void* d_ws, size_t ws_size,
                              hipStream_t stream)
{
    const float* x      = (const float*)d_in[0];   // (1,5,24,48,128)
    const float* qkv_w  = (const float*)d_in[1];   // (384,128)
    const float* qkv_b  = (const float*)d_in[2];   // (384,)
    const float* proj_w = (const float*)d_in[3];   // (128,128)
    const float* proj_b = (const float*)d_in[4];   // (128,)
    float* out = (float*)d_out;                    // (P,128)

    float* qkv  = (float*)d_ws;                    // P*384 floats
    float* attn = qkv + (size_t)NPOS * 384;        // P*128 floats

    // QKV: (5760x128) @ (384x128)^T + b -> (5760x384)
    {
        dim3 grid(384 / 64, NPOS / 64);
        gemm_bias_kernel<64, 64, 64><<<grid, 256, 0, stream>>>(
            x, DIMC, qkv_w, DIMC, qkv_b, qkv, 384, NPOS, 384, DIMC);
    }

    // Fused neighborhood attention
    attn_kernel<<<NPOS, 256, 0, stream>>>(qkv, attn);

    // Proj: (5760x128) @ (128x128)^T + b -> (5760x128)
    {
        dim3 grid(128 / 64, NPOS / 64);
        gemm_bias_kernel<64, 64, 64><<<grid, 256, 0, stream>>>(
            attn, DIMC, proj_w, DIMC, proj_b, out, DIMC, NPOS, DIMC, DIMC);
    }
}

// Round 2
// 130.408 us; speedup vs baseline: 1.5993x; 1.5993x over previous
//
#include <hip/hip_runtime.h>
#include <hip/hip_bf16.h>
#include <cstddef>

// Problem constants
#define DIMC   128
#define NHEADS 8
#define HDIM   16
#define DD     5
#define HH     24
#define WW_    48
#define NPOS   (DD * HH * WW_)     // 5760
#define NNB    245                 // 5*7*7
#define SCALE  0.25f

// Attention tiling
#define TH 4
#define TW 4
#define UH (TH + 6)                // 10
#define UW (TW + 6)                // 10
#define UR (DD * UH * UW)          // 500 union rows
#define KVPAD 36                   // 32 floats + 4 pad (16B-aligned, breaks bank aliasing)

// ---------------------------------------------------------------------------
// GEMM (K=128 fixed): C[M][N] = A[M][128] @ B[N][128]^T + bias[N]
// BM=BN=64, 256 threads, 4x4 micro-tile strided by 16, dot4 over k-quads.
// Whole K staged once (no K-loop). Row pad 128->132 keeps b128 reads 16B
// aligned and fragment reads <=2-way bank aliased (free on CDNA4).
// ---------------------------------------------------------------------------
__global__ __launch_bounds__(256, 2) void gemm128_kernel(
    const float* __restrict__ A,
    const float* __restrict__ B,
    const float* __restrict__ bias,
    float* __restrict__ C, int ldc)
{
    __shared__ __align__(16) float As[64][132];
    __shared__ __align__(16) float Bs[64][132];

    const int tid = threadIdx.x;
    const int bm  = blockIdx.y * 64;
    const int bn  = blockIdx.x * 64;

    // stage: 64 rows x 32 float4 per matrix; lanes cover 2 rows x 32 quads
    #pragma unroll
    for (int i = tid; i < 2048; i += 256) {
        const int r  = i >> 5;        // 0..63
        const int c4 = i & 31;        // 0..31
        const float4 va = *(const float4*)(A + (size_t)(bm + r) * DIMC + c4 * 4);
        *(float4*)(&As[r][c4 * 4]) = va;
        const float4 vb = *(const float4*)(B + (size_t)(bn + r) * DIMC + c4 * 4);
        *(float4*)(&Bs[r][c4 * 4]) = vb;
    }
    __syncthreads();

    const int tx = tid & 15;   // N frags at tx, tx+16, tx+32, tx+48
    const int ty = tid >> 4;   // hmm 0..15; M frags at ty, ty+16, ...

    float acc[4][4] = {};

    #pragma unroll 8
    for (int kq = 0; kq < 32; ++kq) {
        float4 a[4], b[4];
        #pragma unroll
        for (int i = 0; i < 4; ++i) a[i] = *(const float4*)(&As[ty + i * 16][kq * 4]);
        #pragma unroll
        for (int j = 0; j < 4; ++j) b[j] = *(const float4*)(&Bs[tx + j * 16][kq * 4]);
        #pragma unroll
        for (int i = 0; i < 4; ++i)
            #pragma unroll
            for (int j = 0; j < 4; ++j) {
                acc[i][j] += a[i].x * b[j].x;
                acc[i][j] += a[i].y * b[j].y;
                acc[i][j] += a[i].z * b[j].z;
                acc[i][j] += a[i].w * b[j].w;
            }
    }

    #pragma unroll
    for (int i = 0; i < 4; ++i) {
        const int row = bm + ty + i * 16;
        float* crow = C + (size_t)row * ldc + bn;
        #pragma unroll
        for (int j = 0; j < 4; ++j) {
            const int col = tx + j * 16;
            crow[col] = acc[i][j] + bias[bn + col];
        }
    }
}

// ---------------------------------------------------------------------------
// Fused neighborhood attention.
// Grid: (72 spatial tiles of 4x4, 8 heads). Block: 256 threads.
// Key fact: depth window (5) == D, so all 5 depth-positions at a given (y,x)
// share the SAME 245 neighbor rows (d' x 7 x 7). Each thread keeps q/acc for
// 5 depth-positions in registers -> every LDS k/v read amortized 5x.
// Thread map: pc = tid>>4 (which of 16 (ty,tx)), chunk = tid&15 (neighbor
// subset). Softmax uses fixed-shift raw exp (shift cancels in normalization).
// ---------------------------------------------------------------------------
__global__ __launch_bounds__(256, 2) void attn_kernel(
    const float* __restrict__ qkv,
    float* __restrict__ attn_out)
{
    __shared__ __align__(16) float kv_s[UR][KVPAD];   // 72 KB
    __shared__ __align__(16) float q_s[TH * TW * DD][16]; // 5 KB

    const int tile = blockIdx.x;             // 0..71
    const int h    = blockIdx.y;             // head
    const int ty0  = (tile / (WW_ / TW)) * TH;
    const int tx0  = (tile % (WW_ / TW)) * TW;
    const int tid  = threadIdx.x;

    // ---- stage union k/v: 500 rows x 8 float4 (4 k + 4 v) ----
    for (int i = tid; i < UR * 8; i += 256) {
        const int row = i >> 3;
        const int seg = i & 7;
        const int dp = row / (UH * UW);
        const int rr = row % (UH * UW);
        const int yy = rr / UW;
        const int xx = rr % UW;
        int y = ty0 - 3 + yy; y += (y < 0) ? HH : 0;  y -= (y >= HH) ? HH : 0;
        int x = tx0 - 3 + xx; x += (x < 0) ? WW_ : 0; x -= (x >= WW_) ? WW_ : 0;
        const int g = (dp * HH + y) * WW_ + x;
        // seg 0-3: k quad, seg 4-7: v quad
        const float4 val = *(const float4*)(qkv + (size_t)g * 384 + 128
                                            + ((seg >> 2) << 7) + h * HDIM + (seg & 3) * 4);
        *(float4*)(&kv_s[row][((seg >> 2) << 4) + (seg & 3) * 4]) = val;
    }
    // ---- stage q: 80 positions x 4 float4 ----
    for (int i = tid; i < TH * TW * DD * 4; i += 256) {
        const int p = i >> 2;       // 0..79 = (d*4+ty)*4+tx
        const int c = i & 3;
        const int d = p >> 4;
        const int r = p & 15;
        const int yy = r >> 2;
        const int xx = r & 3;
        const int g = (d * HH + ty0 + yy) * WW_ + tx0 + xx;
        *(float4*)(&q_s[p][c * 4]) = *(const float4*)(qkv + (size_t)g * 384 + h * HDIM + c * 4);
    }
    __syncthreads();

    const int pc    = tid >> 4;   // 0..15
    const int chunk = tid & 15;   // 0..15
    const int pty   = pc >> 2;    // 0..3
    const int ptx   = pc & 3;     // 0..3

    // q for all 5 depths into registers (80 VGPRs)
    float q[5][16];
    #pragma unroll
    for (int d = 0; d < 5; ++d) {
        const float4* qp = (const float4*)q_s[(d * 4 + pty) * 4 + ptx];
        const float4 q0 = qp[0], q1 = qp[1], q2 = qp[2], q3 = qp[3];
        q[d][0] = q0.x; q[d][1] = q0.y; q[d][2]  = q0.z; q[d][3]  = q0.w;
        q[d][4] = q1.x; q[d][5] = q1.y; q[d][6]  = q1.z; q[d][7]  = q1.w;
        q[d][8] = q2.x; q[d][9] = q2.y; q[d][10] = q2.z; q[d][11] = q2.w;
        q[d][12] = q3.x; q[d][13] = q3.y; q[d][14] = q3.z; q[d][15] = q3.w;
    }

    float acc[5][16] = {};
    float l[5] = {};

    // neighbor loop: j = (d', oh, ow); each row serves all 5 depth-positions
    for (int j = chunk; j < NNB; j += 16) {
        const int dp = j / 49;
        const int r  = j % 49;
        const int oh = r / 7;
        const int ow = r % 7;
        const int row = (dp * UH + pty + oh) * UW + ptx + ow;
        const float* kp = kv_s[row];
        const float4 k0 = *(const float4*)(kp + 0);
        const float4 k1 = *(const float4*)(kp + 4);
        const float4 k2 = *(const float4*)(kp + 8);
        const float4 k3 = *(const float4*)(kp + 12);
        const float4 v0 = *(const float4*)(kp + 16);
        const float4 v1 = *(const float4*)(kp + 20);
        const float4 v2 = *(const float4*)(kp + 24);
        const float4 v3 = *(const float4*)(kp + 28);
        #pragma unroll
        for (int d = 0; d < 5; ++d) {
            float s = q[d][0]  * k0.x + q[d][1]  * k0.y + q[d][2]  * k0.z + q[d][3]  * k0.w
                    + q[d][4]  * k1.x + q[d][5]  * k1.y + q[d][6]  * k1.z + q[d][7]  * k1.w
                    + q[d][8]  * k2.x + q[d][9]  * k2.y + q[d][10] * k2.z + q[d][11] * k2.w
                    + q[d][12] * k3.x + q[d][13] * k3.y + q[d][14] * k3.z + q[d][15] * k3.w;
            const float e = __expf(fmaf(s, SCALE, -8.0f));  // shift cancels in softmax
            l[d] += e;
            acc[d][0]  += e * v0.x; acc[d][1]  += e * v0.y;
            acc[d][2]  += e * v0.z; acc[d][3]  += e * v0.w;
            acc[d][4]  += e * v1.x; acc[d][5]  += e * v1.y;
            acc[d][6]  += e * v1.z; acc[d][7]  += e * v1.w;
            acc[d][8]  += e * v2.x; acc[d][9]  += e * v2.y;
            acc[d][10] += e * v2.z; acc[d][11] += e * v2.w;
            acc[d][12] += e * v3.x; acc[d][13] += e * v3.y;
            acc[d][14] += e * v3.z; acc[d][15] += e * v3.w;
        }
    }

    // butterfly-reduce across the 16 chunk lanes (16-aligned groups in-wave)
    #pragma unroll
    for (int m = 8; m >= 1; m >>= 1) {
        #pragma unroll
        for (int d = 0; d < 5; ++d) {
            l[d] += __shfl_xor(l[d], m);
            #pragma unroll
            for (int i = 0; i < 16; ++i)
                acc[d][i] += __shfl_xor(acc[d][i], m);
        }
    }

    // lanes chunk==d write depth d (all lanes hold full sums after butterfly)
    #pragma unroll
    for (int d = 0; d < 5; ++d) {
        if (chunk == d) {
            const float inv = 1.0f / l[d];
            const int g = (d * HH + ty0 + pty) * WW_ + tx0 + ptx;
            float* op = attn_out + (size_t)g * DIMC + h * HDIM;
            float4 o0 = make_float4(acc[d][0]  * inv, acc[d][1]  * inv, acc[d][2]  * inv, acc[d][3]  * inv);
            float4 o1 = make_float4(acc[d][4]  * inv, acc[d][5]  * inv, acc[d][6]  * inv, acc[d][7]  * inv);
            float4 o2 = make_float4(acc[d][8]  * inv, acc[d][9]  * inv, acc[d][10] * inv, acc[d][11] * inv);
            float4 o3 = make_float4(acc[d][12] * inv, acc[d][13] * inv, acc[d][14] * inv, acc[d][15] * inv);
            *(float4*)(op + 0)  = o0;
            *(float4*)(op + 4)  = o1;
            *(float4*)(op + 8)  = o2;
            *(float4*)(op + 12) = o3;
        }
    }
}

// ---------------------------------------------------------------------------
extern "C" void kernel_launch(void* const* d_in, const int* in_sizes, int n_in,
                              void* d_out, int out_size, void* d_ws, size_t ws_size,
                              hipStream_t stream)
{
    const float* x      = (const float*)d_in[0];
    const float* qkv_w  = (const float*)d_in[1];
    const float* qkv_b  = (const float*)d_in[2];
    const float* proj_w = (const float*)d_in[3];
    const float* proj_b = (const float*)d_in[4];
    float* out = (float*)d_out;

    float* qkv  = (float*)d_ws;                    // 5760*384 floats
    float* attn = qkv + (size_t)NPOS * 384;        // 5760*128 floats

    // QKV: (5760x128) @ (384x128)^T + b
    {
        dim3 grid(384 / 64, NPOS / 64);
        gemm128_kernel<<<grid, 256, 0, stream>>>(x, qkv_w, qkv_b, qkv, 384);
    }
    // fused neighborhood attention
    {
        dim3 grid((HH / TH) * (WW_ / TW), NHEADS);
        attn_kernel<<<grid, 256, 0, stream>>>(qkv, attn);
    }
    // proj: (5760x128) @ (128x128)^T + b
    {
        dim3 grid(DIMC / 64, NPOS / 64);
        gemm128_kernel<<<grid, 256, 0, stream>>>(attn, proj_w, proj_b, out, DIMC);
    }
}

// Round 4
// 128.164 us; speedup vs baseline: 1.6273x; 1.0175x over previous
//
#include <hip/hip_runtime.h>
#include <hip/hip_bf16.h>
#include <cstddef>

// Problem constants
#define DIMC   128
#define NHEADS 8
#define HDIM   16
#define DD     5
#define HH     24
#define WW_    48
#define NPOS   (DD * HH * WW_)     // 5760
#define SCALE  0.25f

typedef short  bf16x8 __attribute__((ext_vector_type(8)));
typedef float  f32x4  __attribute__((ext_vector_type(4)));

__device__ __forceinline__ unsigned short f2bf(float f) {
    unsigned u = __float_as_uint(f);
    u = (u + 0x7FFFu + ((u >> 16) & 1u)) >> 16;   // RNE
    return (unsigned short)u;
}
__device__ __forceinline__ float bf2f(unsigned short s) {
    return __uint_as_float(((unsigned)s) << 16);
}

// ---------------------------------------------------------------------------
// prep: fp32 -> bf16 3-term split expansion.
//   A-side (x):       [hi(128) | lo(128) | hi(128)]
//   B-side (weights): [hi(128) | hi(128) | lo(128)]
// K-segment pairing in the GEMM: hi*hi + lo*hi + hi*lo  ==  full product
// minus the negligible lo*lo (~2^-18). (Round-3 bug: all buffers were
// [hi|lo|hi], pairing hi*hi twice -> 2x product -> absmax 13.9.)
// grid*block == 200704 float4 work items exactly.
// ---------------------------------------------------------------------------
__global__ __launch_bounds__(256) void prep_kernel(
    const float* __restrict__ x,
    const float* __restrict__ wq,
    const float* __restrict__ wp,
    unsigned short* __restrict__ Axq,
    unsigned short* __restrict__ Bxq,
    unsigned short* __restrict__ Bxp)
{
    const int i = blockIdx.x * 256 + threadIdx.x;   // one float4 each
    const bool isA = (i < 184320);
    const float* src; unsigned short* dst; int rel;
    if (isA)             { src = x;  dst = Axq; rel = i; }
    else if (i < 196608) { src = wq; dst = Bxq; rel = i - 184320; }
    else                 { src = wp; dst = Bxp; rel = i - 196608; }
    const int row = rel >> 5;       // 32 float4 per 128-col row
    const int c4  = rel & 31;
    const float4 v = *(const float4*)(src + (size_t)row * 128 + c4 * 4);
    ushort4 hi, lo;
    hi.x = f2bf(v.x); hi.y = f2bf(v.y); hi.z = f2bf(v.z); hi.w = f2bf(v.w);
    lo.x = f2bf(v.x - bf2f(hi.x));
    lo.y = f2bf(v.y - bf2f(hi.y));
    lo.z = f2bf(v.z - bf2f(hi.z));
    lo.w = f2bf(v.w - bf2f(hi.w));
    unsigned short* p = dst + (size_t)row * 384 + c4 * 4;
    if (isA) {
        *(ushort4*)(p)       = hi;
        *(ushort4*)(p + 128) = lo;
        *(ushort4*)(p + 256) = hi;
    } else {
        *(ushort4*)(p)       = hi;
        *(ushort4*)(p + 128) = hi;
        *(ushort4*)(p + 256) = lo;
    }
}

// ---------------------------------------------------------------------------
// MFMA GEMM: C[M][N] = A'[M][384] @ B'[N][384]^T + bias, fp32 out.
// Block 128x64, 4 waves; B' slice in LDS, A fragments streamed from global.
// ---------------------------------------------------------------------------
__global__ __launch_bounds__(256, 3) void gemm_mfma_kernel(
    const unsigned short* __restrict__ Ax,
    const unsigned short* __restrict__ Bx,
    const float* __restrict__ bias,
    float* __restrict__ C, int ldc)
{
    __shared__ __align__(16) unsigned short Bs[64][392];  // +16B row pad

    const int tid = threadIdx.x;
    const int bn  = blockIdx.x * 64;
    const int bm  = blockIdx.y * 128;

    for (int i = tid; i < 64 * 48; i += 256) {
        const int r = i / 48, s = i % 48;
        *(ulonglong2*)(&Bs[r][s * 8]) =
            *(const ulonglong2*)(Bx + (size_t)(bn + r) * 384 + s * 8);
    }
    __syncthreads();

    const int w    = tid >> 6;
    const int lane = tid & 63;
    const int ln   = lane & 15;
    const int quad = lane >> 4;

    f32x4 acc[2][4] = {};
    const unsigned short* arow0 = Ax + (size_t)(bm + w * 32 + ln) * 384 + quad * 8;
    const unsigned short* arow1 = arow0 + 16 * 384;

    #pragma unroll
    for (int kc = 0; kc < 12; ++kc) {
        const bf16x8 a0 = *(const bf16x8*)(arow0 + kc * 32);
        const bf16x8 a1 = *(const bf16x8*)(arow1 + kc * 32);
        #pragma unroll
        for (int nt = 0; nt < 4; ++nt) {
            const bf16x8 b = *(const bf16x8*)(&Bs[nt * 16 + ln][kc * 32 + quad * 8]);
            acc[0][nt] = __builtin_amdgcn_mfma_f32_16x16x32_bf16(a0, b, acc[0][nt], 0, 0, 0);
            acc[1][nt] = __builtin_amdgcn_mfma_f32_16x16x32_bf16(a1, b, acc[1][nt], 0, 0, 0);
        }
    }

    #pragma unroll
    for (int mi = 0; mi < 2; ++mi)
        #pragma unroll
        for (int nt = 0; nt < 4; ++nt) {
            const int col = bn + nt * 16 + ln;
            const float bv = bias[col];
            #pragma unroll
            for (int r = 0; r < 4; ++r) {
                const int row = bm + w * 32 + mi * 16 + quad * 4 + r;
                C[(size_t)row * ldc + col] = acc[mi][nt][r] + bv;
            }
        }
}

// ---------------------------------------------------------------------------
// Fused neighborhood attention, MFMA version.
// Grid (72 tiles of 4x4, 8 heads), 256 threads (4 waves), 2 blocks/CU.
// M = 80 rows (m = d*16 + sy*4+sx), N = 512 union cols (500 real).
// Scores: A=[Qhi|Qlo] x B=[K|K] (compensated q, bf16 k). Raw exp (no max
// pass; logits bounded). P wave-private in LDS -> PV MFMA with V transposed.
// Output written directly as bf16 [hi|lo|hi] rows of A'proj (A-side layout).
// ---------------------------------------------------------------------------
__global__ __launch_bounds__(256, 2) void attn_kernel(
    const float* __restrict__ qkv,          // [5760][384] fp32
    unsigned short* __restrict__ Ap)        // [5760][384] bf16 hi|lo|hi
{
    __shared__ __align__(16) unsigned short Kb[512][24];  // [k(16)|pad(8)]
    __shared__ __align__(16) unsigned short Vt[16][520];  // transposed V
    __shared__ __align__(16) unsigned short Qb[80][40];   // [hi(16)|lo(16)|pad(8)]
    __shared__ __align__(16) unsigned short Pb[80][136];  // P chunk (128 cols)
    __shared__ float red_l[4][80];

    const int tile = blockIdx.x;
    const int h    = blockIdx.y;
    const int ty0  = (tile / 12) * 4;
    const int tx0  = (tile % 12) * 4;
    const int tid  = threadIdx.x;

    // ---- stage K (bf16) and V (bf16, transposed); zero pad rows ----
    for (int i = tid; i < 512 * 8; i += 256) {
        const int u = i >> 3, seg = i & 7;
        if (u < 500) {
            const int dp = u / 100, rr = u % 100;
            const int yy = rr / 10, xx = rr % 10;
            int y = ty0 - 3 + yy; if (y < 0) y += HH;  if (y >= HH) y -= HH;
            int x = tx0 - 3 + xx; if (x < 0) x += WW_; if (x >= WW_) x -= WW_;
            const float* base = qkv + (size_t)((dp * HH + y) * WW_ + x) * 384 + h * HDIM;
            if (seg < 4) {
                const float4 kv = *(const float4*)(base + 128 + seg * 4);
                ushort4 kb;
                kb.x = f2bf(kv.x); kb.y = f2bf(kv.y); kb.z = f2bf(kv.z); kb.w = f2bf(kv.w);
                *(ushort4*)(&Kb[u][seg * 4]) = kb;
            } else {
                const int c0 = (seg - 4) * 4;
                const float4 vv = *(const float4*)(base + 256 + c0);
                Vt[c0 + 0][u] = f2bf(vv.x);
                Vt[c0 + 1][u] = f2bf(vv.y);
                Vt[c0 + 2][u] = f2bf(vv.z);
                Vt[c0 + 3][u] = f2bf(vv.w);
            }
        } else {
            if (seg < 4) { *(ushort4*)(&Kb[u][seg * 4]) = (ushort4){0, 0, 0, 0}; }
            else {
                const int c0 = (seg - 4) * 4;
                Vt[c0][u] = 0; Vt[c0 + 1][u] = 0; Vt[c0 + 2][u] = 0; Vt[c0 + 3][u] = 0;
            }
        }
    }
    // ---- stage Q as [hi|lo] ----
    for (int i = tid; i < 320; i += 256) {
        const int p = i >> 2, q4 = i & 3;
        const int d = p >> 4, s = p & 15;
        const int sy = s >> 2, sx = s & 3;
        const float* base = qkv + (size_t)((d * HH + ty0 + sy) * WW_ + tx0 + sx) * 384 + h * HDIM;
        const float4 qv = *(const float4*)(base + q4 * 4);
        ushort4 hi, lo;
        hi.x = f2bf(qv.x); hi.y = f2bf(qv.y); hi.z = f2bf(qv.z); hi.w = f2bf(qv.w);
        lo.x = f2bf(qv.x - bf2f(hi.x));
        lo.y = f2bf(qv.y - bf2f(hi.y));
        lo.z = f2bf(qv.z - bf2f(hi.z));
        lo.w = f2bf(qv.w - bf2f(hi.w));
        *(ushort4*)(&Qb[p][q4 * 4])      = hi;
        *(ushort4*)(&Qb[p][16 + q4 * 4]) = lo;
    }
    __syncthreads();

    const int w    = tid >> 6;
    const int lane = tid & 63;
    const int ln   = lane & 15;
    const int quad = lane >> 4;

    f32x4 Ow[5] = {};
    float lpart[5][4] = {};

    for (int pass = 0; pass < 4; ++pass) {
        // ---- scores + mask + exp for this wave's 2 n-tiles ----
        #pragma unroll
        for (int t = 0; t < 2; ++t) {
            const int ntile = pass * 8 + w * 2 + t;
            const int u = ntile * 16 + ln;
            const bool valid_u = (u < 500);
            const int rr = u % 100;
            const int uy = rr / 10, ux = rr % 10;
            const bool my = ((unsigned)(uy - quad) <= 6u);  // sy == quad
            bool mr[4];
            #pragma unroll
            for (int r = 0; r < 4; ++r)                      // sx == r
                mr[r] = valid_u && my && ((unsigned)(ux - r) <= 6u);

            const bf16x8 bfr = *(const bf16x8*)(&Kb[u][(quad & 1) * 8]);
            f32x4 sc[5];
            #pragma unroll
            for (int mt = 0; mt < 5; ++mt) {
                const bf16x8 afr = *(const bf16x8*)(&Qb[mt * 16 + ln][quad * 8]);
                sc[mt] = __builtin_amdgcn_mfma_f32_16x16x32_bf16(
                    afr, bfr, (f32x4){0.f, 0.f, 0.f, 0.f}, 0, 0, 0);
            }
            const int pcol = (w * 2 + t) * 16 + ln;
            #pragma unroll
            for (int mt = 0; mt < 5; ++mt) {
                #pragma unroll
                for (int r = 0; r < 4; ++r) {
                    const float e = mr[r] ? __expf(sc[mt][r] * SCALE) : 0.f;
                    const unsigned short pb = f2bf(e);
                    lpart[mt][r] += bf2f(pb);
                    Pb[mt * 16 + quad * 4 + r][pcol] = pb;
                }
            }
        }
        __syncthreads();
        // ---- PV: wave's own 32-col slice (k-local = w*32) ----
        #pragma unroll
        for (int mt = 0; mt < 5; ++mt) {
            const bf16x8 afr = *(const bf16x8*)(&Pb[mt * 16 + ln][w * 32 + quad * 8]);
            const bf16x8 bfr = *(const bf16x8*)(&Vt[ln][pass * 128 + w * 32 + quad * 8]);
            Ow[mt] = __builtin_amdgcn_mfma_f32_16x16x32_bf16(afr, bfr, Ow[mt], 0, 0, 0);
        }
        __syncthreads();
    }

    // ---- reduce row-sums across the 16 col-lanes, then across waves ----
    #pragma unroll
    for (int m = 1; m <= 8; m <<= 1)
        #pragma unroll
        for (int mt = 0; mt < 5; ++mt)
            #pragma unroll
            for (int r = 0; r < 4; ++r)
                lpart[mt][r] += __shfl_xor(lpart[mt][r], m);
    if (ln == 0) {
        #pragma unroll
        for (int mt = 0; mt < 5; ++mt)
            #pragma unroll
            for (int r = 0; r < 4; ++r)
                red_l[w][mt * 16 + quad * 4 + r] = lpart[mt][r];
    }
    __syncthreads();

    // ---- cross-wave O reduction (reuse Pb as fp32 buffer) ----
    float* redO = (float*)&Pb[0][0];   // 4*80*16 fp32 = 20480 B <= 21760 B
    #pragma unroll
    for (int mt = 0; mt < 5; ++mt)
        #pragma unroll
        for (int r = 0; r < 4; ++r)
            redO[((size_t)w * 80 + mt * 16 + quad * 4 + r) * 16 + ln] = Ow[mt][r];
    __syncthreads();

    for (int i = tid; i < 1280; i += 256) {
        const int m = i >> 4, c = i & 15;
        const float o = redO[(size_t)(m) * 16 + c]
                      + redO[(size_t)(80 + m) * 16 + c]
                      + redO[(size_t)(160 + m) * 16 + c]
                      + redO[(size_t)(240 + m) * 16 + c];
        const float ls = red_l[0][m] + red_l[1][m] + red_l[2][m] + red_l[3][m];
        const float val = o / ls;
        const int d = m >> 4, s = m & 15;
        const int sy = s >> 2, sx = s & 3;
        const size_t g = (size_t)((d * HH + ty0 + sy) * WW_ + (tx0 + sx));
        const unsigned short hi = f2bf(val);
        const unsigned short lo = f2bf(val - bf2f(hi));
        unsigned short* row = Ap + g * 384 + h * HDIM + c;
        row[0]   = hi;
        row[128] = lo;
        row[256] = hi;
    }
}

// ---------------------------------------------------------------------------
extern "C" void kernel_launch(void* const* d_in, const int* in_sizes, int n_in,
                              void* d_out, int out_size, void* d_ws, size_t ws_size,
                              hipStream_t stream)
{
    const float* x      = (const float*)d_in[0];
    const float* qkv_w  = (const float*)d_in[1];
    const float* qkv_b  = (const float*)d_in[2];
    const float* proj_w = (const float*)d_in[3];
    const float* proj_b = (const float*)d_in[4];
    float* out = (float*)d_out;

    char* ws = (char*)d_ws;
    float*          qkv = (float*)ws;                                  ws += (size_t)NPOS * 384 * 4;   // 8.85 MB
    unsigned short* Axq = (unsigned short*)ws;                         ws += (size_t)NPOS * 384 * 2;   // 4.42 MB
    unsigned short* Axp = (unsigned short*)ws;                         ws += (size_t)NPOS * 384 * 2;   // 4.42 MB
    unsigned short* Bxq = (unsigned short*)ws;                         ws += (size_t)384 * 384 * 2;
    unsigned short* Bxp = (unsigned short*)ws;                         ws += (size_t)128 * 384 * 2;

    // 1. hi/lo expansion of x (A-side), qkv_w/proj_w (B-side)
    prep_kernel<<<784, 256, 0, stream>>>(x, qkv_w, proj_w, Axq, Bxq, Bxp);

    // 2. QKV GEMM: (5760x384bf16) @ (384x384bf16)^T -> fp32
    {
        dim3 grid(384 / 64, NPOS / 128);
        gemm_mfma_kernel<<<grid, 256, 0, stream>>>(Axq, Bxq, qkv_b, qkv, 384);
    }
    // 3. fused neighborhood attention -> Axp (bf16 hi|lo|hi)
    {
        dim3 grid(72, NHEADS);
        attn_kernel<<<grid, 256, 0, stream>>>(qkv, Axp);
    }
    // 4. proj GEMM: (5760x384bf16) @ (128x384bf16)^T -> out
    {
        dim3 grid(DIMC / 64, NPOS / 128);
        gemm_mfma_kernel<<<grid, 256, 0, stream>>>(Axp, Bxp, proj_b, out, DIMC);
    }
}

// Round 5
// 107.384 us; speedup vs baseline: 1.9421x; 1.1935x over previous
//
#include <hip/hip_runtime.h>
#include <hip/hip_bf16.h>
#include <cstddef>

// Problem constants
#define DIMC   128
#define NHEADS 8
#define HDIM   16
#define DD     5
#define HH     24
#define WW_    48
#define NPOS   (DD * HH * WW_)     // 5760
#define SCALE  0.25f

typedef short  bf16x8 __attribute__((ext_vector_type(8)));
typedef float  f32x4  __attribute__((ext_vector_type(4)));

__device__ __forceinline__ unsigned short f2bf(float f) {
    unsigned u = __float_as_uint(f);
    u = (u + 0x7FFFu + ((u >> 16) & 1u)) >> 16;   // RNE
    return (unsigned short)u;
}
__device__ __forceinline__ float bf2f(unsigned short s) {
    return __uint_as_float(((unsigned)s) << 16);
}

// ---------------------------------------------------------------------------
// prep: fp32 -> bf16 3-term split expansion.
//   A-side (x):       [hi(128) | lo(128) | hi(128)]
//   B-side (weights): [hi(128) | hi(128) | lo(128)]
// Pairing: hi*hi + lo*hi + hi*lo == full product minus negligible lo*lo.
// ---------------------------------------------------------------------------
__global__ __launch_bounds__(256) void prep_kernel(
    const float* __restrict__ x,
    const float* __restrict__ wq,
    const float* __restrict__ wp,
    unsigned short* __restrict__ Axq,
    unsigned short* __restrict__ Bxq,
    unsigned short* __restrict__ Bxp)
{
    const int i = blockIdx.x * 256 + threadIdx.x;   // one float4 each
    const bool isA = (i < 184320);
    const float* src; unsigned short* dst; int rel;
    if (isA)             { src = x;  dst = Axq; rel = i; }
    else if (i < 196608) { src = wq; dst = Bxq; rel = i - 184320; }
    else                 { src = wp; dst = Bxp; rel = i - 196608; }
    const int row = rel >> 5;
    const int c4  = rel & 31;
    const float4 v = *(const float4*)(src + (size_t)row * 128 + c4 * 4);
    ushort4 hi, lo;
    hi.x = f2bf(v.x); hi.y = f2bf(v.y); hi.z = f2bf(v.z); hi.w = f2bf(v.w);
    lo.x = f2bf(v.x - bf2f(hi.x));
    lo.y = f2bf(v.y - bf2f(hi.y));
    lo.z = f2bf(v.z - bf2f(hi.z));
    lo.w = f2bf(v.w - bf2f(hi.w));
    unsigned short* p = dst + (size_t)row * 384 + c4 * 4;
    if (isA) {
        *(ushort4*)(p)       = hi;
        *(ushort4*)(p + 128) = lo;
        *(ushort4*)(p + 256) = hi;
    } else {
        *(ushort4*)(p)       = hi;
        *(ushort4*)(p + 128) = hi;
        *(ushort4*)(p + 256) = lo;
    }
}

// ---------------------------------------------------------------------------
// MFMA GEMM: C[M][N] = A'[M][384] @ B'[N][384]^T + bias.
// MI: rows per wave / 16 (block covers 64*MI rows). EPI 0: fp32 C out.
// EPI 1 (QKV): emit Q as bf16 hi/lo pairs (Qhl[pos][h*32 + {hi16|lo16}]),
// K and V as bf16 (Kbf/Vbf[pos][128]) — attention consumes bf16 directly,
// no fp32 qkv intermediate.
// ---------------------------------------------------------------------------
template <int MI, int EPI>
__global__ __launch_bounds__(256, 3) void gemm_mfma_kernel(
    const unsigned short* __restrict__ Ax,
    const unsigned short* __restrict__ Bx,
    const float* __restrict__ bias,
    float* __restrict__ C, int ldc,
    unsigned short* __restrict__ Qhl,
    unsigned short* __restrict__ Kbf,
    unsigned short* __restrict__ Vbf)
{
    __shared__ __align__(16) unsigned short Bs[64][392];  // +16B row pad

    const int tid = threadIdx.x;
    const int bn  = blockIdx.x * 64;
    const int bm  = blockIdx.y * 64 * MI;

    for (int i = tid; i < 64 * 48; i += 256) {
        const int r = i / 48, s = i % 48;
        *(ulonglong2*)(&Bs[r][s * 8]) =
            *(const ulonglong2*)(Bx + (size_t)(bn + r) * 384 + s * 8);
    }
    __syncthreads();

    const int w    = tid >> 6;
    const int lane = tid & 63;
    const int ln   = lane & 15;
    const int quad = lane >> 4;

    f32x4 acc[MI][4] = {};
    const unsigned short* arow[MI];
    #pragma unroll
    for (int mi = 0; mi < MI; ++mi)
        arow[mi] = Ax + (size_t)(bm + w * 16 * MI + mi * 16 + ln) * 384 + quad * 8;

    #pragma unroll
    for (int kc = 0; kc < 12; ++kc) {
        bf16x8 a[MI];
        #pragma unroll
        for (int mi = 0; mi < MI; ++mi) a[mi] = *(const bf16x8*)(arow[mi] + kc * 32);
        #pragma unroll
        for (int nt = 0; nt < 4; ++nt) {
            const bf16x8 b = *(const bf16x8*)(&Bs[nt * 16 + ln][kc * 32 + quad * 8]);
            #pragma unroll
            for (int mi = 0; mi < MI; ++mi)
                acc[mi][nt] = __builtin_amdgcn_mfma_f32_16x16x32_bf16(a[mi], b, acc[mi][nt], 0, 0, 0);
        }
    }

    #pragma unroll
    for (int mi = 0; mi < MI; ++mi)
        #pragma unroll
        for (int nt = 0; nt < 4; ++nt) {
            const int col = bn + nt * 16 + ln;
            const float bv = bias[col];
            #pragma unroll
            for (int r = 0; r < 4; ++r) {
                const int row = bm + w * 16 * MI + mi * 16 + quad * 4 + r;
                const float val = acc[mi][nt][r] + bv;
                if (EPI == 0) {
                    C[(size_t)row * ldc + col] = val;
                } else {
                    if (col < 128) {               // q -> hi/lo pair
                        const int h = col >> 4, ci = col & 15;
                        const unsigned short hi = f2bf(val);
                        Qhl[(size_t)row * 256 + h * 32 + ci]      = hi;
                        Qhl[(size_t)row * 256 + h * 32 + 16 + ci] = f2bf(val - bf2f(hi));
                    } else if (col < 256) {        // k -> bf16
                        Kbf[(size_t)row * 128 + (col - 128)] = f2bf(val);
                    } else {                       // v -> bf16
                        Vbf[(size_t)row * 128 + (col - 256)] = f2bf(val);
                    }
                }
            }
        }
}

// ---------------------------------------------------------------------------
// Fused neighborhood attention, transposed-MFMA version.
// Grid (72 tiles of 4x4, 8 heads), 256 threads (4 waves).
// S^T = K(u x 16dup) @ Q^T([hi|lo] 32 x 16m): output col=query m, row=u.
// exp+mask in regs -> wave-private P slab (16m x 32u bf16, no barrier) ->
// O^T = V^T(16c x 32u) @ P^T(32u x 16m). Waves own disjoint u ranges
// (w*128..+127); barriers only at staging (1) and epilogue (2).
// K A-fragments gather directly from global (no K LDS at all), reused
// across all 5 depth m-tiles. LDS 34.5 KB -> 4 blocks/CU by LDS.
// ---------------------------------------------------------------------------
__global__ __launch_bounds__(256, 3) void attn_kernel(
    const unsigned short* __restrict__ Qhl,   // [5760][256] bf16 per-head hi|lo
    const unsigned short* __restrict__ Kbf,   // [5760][128] bf16
    const unsigned short* __restrict__ Vbf,   // [5760][128] bf16
    unsigned short* __restrict__ Ap)          // [5760][384] bf16 hi|lo|hi
{
    // LDS pool (manual layout; redO overlays Vt+Qb after epilogue barrier):
    //   Vt   : ushort[16][520]        @     0  (16640 B)  V^T, u-major rows
    //   Qb   : ushort[80][40]         @ 16640  ( 6400 B)  [hi16|lo16|pad8]
    //   Pw   : ushort[4][2][16][40]   @ 23040  (10240 B)  wave-private P
    //   red_l: float [4][80]          @ 33280  ( 1280 B)
    //   redO : float [4][5*16][16]    @     0  (20480 B)  overlay
    __shared__ __align__(16) char smem[34560];
    unsigned short (*Vt)[520] = (unsigned short(*)[520])smem;
    unsigned short (*Qb)[40]  = (unsigned short(*)[40])(smem + 16640);
    unsigned short* PwBase    = (unsigned short*)(smem + 23040);
    float* red_l              = (float*)(smem + 33280);
    float* redO               = (float*)smem;

    const int tile = blockIdx.x;
    const int h    = blockIdx.y;
    const int ty0  = (tile / 12) * 4;
    const int tx0  = (tile % 12) * 4;
    const int tid  = threadIdx.x;

    // ---- stage V^T (bf16) ----
    for (int i = tid; i < 1024; i += 256) {
        const int u = i >> 1, half = i & 1;
        if (u < 500) {
            const int dp = u / 100;
            const int rr = u - dp * 100;
            const int yy = rr / 10;
            const int xx = rr - yy * 10;
            int y = ty0 - 3 + yy; if (y < 0) y += HH;  if (y >= HH) y -= HH;
            int x = tx0 - 3 + xx; if (x < 0) x += WW_; if (x >= WW_) x -= WW_;
            const int g = (dp * HH + y) * WW_ + x;
            const bf16x8 v = *(const bf16x8*)(Vbf + (size_t)g * 128 + h * 16 + half * 8);
            #pragma unroll
            for (int c = 0; c < 8; ++c) Vt[half * 8 + c][u] = (unsigned short)v[c];
        } else {
            #pragma unroll
            for (int c = 0; c < 8; ++c) Vt[half * 8 + c][u] = 0;
        }
    }
    // ---- stage Q tile (straight bf16 copy) ----
    for (int i = tid; i < 320; i += 256) {
        const int p = i >> 2, seg = i & 3;
        const int d = p >> 4, s = p & 15;
        const int sy = s >> 2, sx = s & 3;
        const int g = (d * HH + ty0 + sy) * WW_ + tx0 + sx;
        *(bf16x8*)(&Qb[p][seg * 8]) = *(const bf16x8*)(Qhl + (size_t)g * 256 + h * 32 + seg * 8);
    }
    __syncthreads();

    const int w    = tid >> 6;
    const int lane = tid & 63;
    const int ln   = lane & 15;
    const int quad = lane >> 4;
    const int sy   = ln >> 2, sx = ln & 3;   // this lane's query (y,x) in tile

    unsigned short* Pw = PwBase + w * 1280;  // [2][16][40]

    // hoist Q B-fragments: B[k=quad*8+j][n=ln] = Qb[mt*16+ln][quad*8+j]
    bf16x8 qf[5];
    #pragma unroll
    for (int mt = 0; mt < 5; ++mt)
        qf[mt] = *(const bf16x8*)(&Qb[mt * 16 + ln][quad * 8]);

    f32x4 Ow[5] = {};
    float lsum[5] = {};

    for (int chunk = 0; chunk < 4; ++chunk) {
        const int u0 = (w * 4 + chunk) * 32;

        // K A-fragments straight from global: A[m=ln][k] with [K|K] channel dup
        int rowa, rowb;
        {
            const int ua = u0 + ln      < 500 ? u0 + ln      : 499;
            const int ub = u0 + 16 + ln < 500 ? u0 + 16 + ln : 499;
            int dp = ua / 100, rr = ua - dp * 100, yy = rr / 10, xx = rr - yy * 10;
            int y = ty0 - 3 + yy; if (y < 0) y += HH;  if (y >= HH) y -= HH;
            int x = tx0 - 3 + xx; if (x < 0) x += WW_; if (x >= WW_) x -= WW_;
            rowa = (dp * HH + y) * WW_ + x;
            dp = ub / 100; rr = ub - dp * 100; yy = rr / 10; xx = rr - yy * 10;
            y = ty0 - 3 + yy; if (y < 0) y += HH;  if (y >= HH) y -= HH;
            x = tx0 - 3 + xx; if (x < 0) x += WW_; if (x >= WW_) x -= WW_;
            rowb = (dp * HH + y) * WW_ + x;
        }
        const bf16x8 ka = *(const bf16x8*)(Kbf + (size_t)rowa * 128 + h * 16 + (quad & 1) * 8);
        const bf16x8 kb = *(const bf16x8*)(Kbf + (size_t)rowb * 128 + h * 16 + (quad & 1) * 8);

        // masks for this lane's 8 score slots: u = u0 + 16*b + 4*quad + r
        bool msk[2][4];
        #pragma unroll
        for (int b = 0; b < 2; ++b)
            #pragma unroll
            for (int r = 0; r < 4; ++r) {
                const int u = u0 + 16 * b + 4 * quad + r;
                const int rr = u % 100;
                const int uy = rr / 10, ux = rr - uy * 10;
                msk[b][r] = (u < 500) && ((unsigned)(uy - sy) <= 6u)
                                      && ((unsigned)(ux - sx) <= 6u);
            }

        // V^T A-fragment for PV (shared across m-tiles this chunk)
        const bf16x8 vf = *(const bf16x8*)(&Vt[ln][u0 + quad * 8]);

        #pragma unroll
        for (int mt = 0; mt < 5; ++mt) {
            f32x4 s0 = __builtin_amdgcn_mfma_f32_16x16x32_bf16(
                ka, qf[mt], (f32x4){0.f, 0.f, 0.f, 0.f}, 0, 0, 0);
            f32x4 s1 = __builtin_amdgcn_mfma_f32_16x16x32_bf16(
                kb, qf[mt], (f32x4){0.f, 0.f, 0.f, 0.f}, 0, 0, 0);

            unsigned short* pw = Pw + (mt & 1) * 640 + ln * 40;
            #pragma unroll
            for (int b = 0; b < 2; ++b) {
                const f32x4 s = b ? s1 : s0;
                unsigned short e[4];
                #pragma unroll
                for (int r = 0; r < 4; ++r) {
                    const float ev = msk[b][r] ? __expf(fmaf(s[r], SCALE, -8.0f)) : 0.f;
                    e[r] = f2bf(ev);
                    lsum[mt] += bf2f(e[r]);
                }
                *(unsigned*)(pw + 16 * b + 4 * quad)     = (unsigned)e[0] | ((unsigned)e[1] << 16);
                *(unsigned*)(pw + 16 * b + 4 * quad + 2) = (unsigned)e[2] | ((unsigned)e[3] << 16);
            }
            // PV: B[k=quad*8+j][n=ln] = P[m=ln][u_loc=quad*8+j]
            const bf16x8 pf = *(const bf16x8*)(Pw + (mt & 1) * 640 + ln * 40 + quad * 8);
            Ow[mt] = __builtin_amdgcn_mfma_f32_16x16x32_bf16(vf, pf, Ow[mt], 0, 0, 0);
        }
    }

    // ---- wave-internal l reduction (sum over quads: lanes ln+16q hold parts)
    #pragma unroll
    for (int mt = 0; mt < 5; ++mt) {
        lsum[mt] += __shfl_xor(lsum[mt], 16);
        lsum[mt] += __shfl_xor(lsum[mt], 32);
    }

    __syncthreads();   // all Vt/Qb/Pw reads done; safe to overlay redO

    if (quad == 0) {
        #pragma unroll
        for (int mt = 0; mt < 5; ++mt) red_l[w * 80 + mt * 16 + ln] = lsum[mt];
    }
    #pragma unroll
    for (int mt = 0; mt < 5; ++mt)
        #pragma unroll
        for (int r = 0; r < 4; ++r)
            redO[(size_t)((w * 5 + mt) * 16 + quad * 4 + r) * 16 + ln] = Ow[mt][r];
    __syncthreads();

    // ---- final: sum 4 wave-partials, normalize, write Ap [hi|lo|hi] ----
    for (int i = tid; i < 1280; i += 256) {
        const int m = i >> 4, c = i & 15;     // m: query 0..79, c: channel
        const int mt = m >> 4, mloc = m & 15;
        float o = 0.f, l = 0.f;
        #pragma unroll
        for (int w4 = 0; w4 < 4; ++w4) {
            o += redO[(size_t)((w4 * 5 + mt) * 16 + c) * 16 + mloc];
            l += red_l[w4 * 80 + m];
        }
        const float val = o / l;
        const int qsy = (mloc >> 2), qsx = mloc & 3;
        const size_t g = (size_t)((mt * HH + ty0 + qsy) * WW_ + (tx0 + qsx));
        const unsigned short hi = f2bf(val);
        const unsigned short lo = f2bf(val - bf2f(hi));
        unsigned short* row = Ap + g * 384 + h * HDIM + c;
        row[0]   = hi;
        row[128] = lo;
        row[256] = hi;
    }
}

// ---------------------------------------------------------------------------
extern "C" void kernel_launch(void* const* d_in, const int* in_sizes, int n_in,
                              void* d_out, int out_size, void* d_ws, size_t ws_size,
                              hipStream_t stream)
{
    const float* x      = (const float*)d_in[0];
    const float* qkv_w  = (const float*)d_in[1];
    const float* qkv_b  = (const float*)d_in[2];
    const float* proj_w = (const float*)d_in[3];
    const float* proj_b = (const float*)d_in[4];
    float* out = (float*)d_out;

    char* ws = (char*)d_ws;
    unsigned short* Axq = (unsigned short*)ws;  ws += (size_t)NPOS * 384 * 2;  // x  hi|lo|hi
    unsigned short* Ap  = (unsigned short*)ws;  ws += (size_t)NPOS * 384 * 2;  // attn out hi|lo|hi
    unsigned short* Bxq = (unsigned short*)ws;  ws += (size_t)384 * 384 * 2;
    unsigned short* Bxp = (unsigned short*)ws;  ws += (size_t)128 * 384 * 2;
    unsigned short* Qhl = (unsigned short*)ws;  ws += (size_t)NPOS * 256 * 2;  // q hi|lo per head
    unsigned short* Kbf = (unsigned short*)ws;  ws += (size_t)NPOS * 128 * 2;
    unsigned short* Vbf = (unsigned short*)ws;  ws += (size_t)NPOS * 128 * 2;

    // 1. hi/lo expansion of x (A-side), qkv_w/proj_w (B-side)
    prep_kernel<<<784, 256, 0, stream>>>(x, qkv_w, proj_w, Axq, Bxq, Bxp);

    // 2. QKV GEMM -> Qhl (bf16 hi/lo), Kbf, Vbf (bf16); no fp32 intermediate
    {
        dim3 grid(384 / 64, NPOS / 128);
        gemm_mfma_kernel<2, 1><<<grid, 256, 0, stream>>>(
            Axq, Bxq, qkv_b, nullptr, 0, Qhl, Kbf, Vbf);
    }
    // 3. fused neighborhood attention -> Ap (bf16 hi|lo|hi)
    {
        dim3 grid(72, NHEADS);
        attn_kernel<<<grid, 256, 0, stream>>>(Qhl, Kbf, Vbf, Ap);
    }
    // 4. proj GEMM: (5760x384bf16) @ (128x384bf16)^T -> out fp32
    {
        dim3 grid(DIMC / 64, NPOS / 64);
        gemm_mfma_kernel<1, 0><<<grid, 256, 0, stream>>>(
            Ap, Bxp, proj_b, out, DIMC, nullptr, nullptr, nullptr);
    }
}